// Round 1
// baseline (190.023 us; speedup 1.0000x reference)
//
#include <hip/hip_runtime.h>

// DR splitting solver. BATCH=4096, N=96 (64 x + 32 s), M=48 (16 eq + 32 ineq).
// JF and Hessian are batch-independent => prox_g1 is an affine map y = P x + Bmat p.
//   S=(I+Q)^{-1}; T=S Jx^T; K2=Jx T+diag(0,I32); R2=K2^{-1}[T^T|E];
//   P=diag(S,I)-[T;E^T]R2; Bmat=[-P[:,:64] | R2^T]   (uses I-P*Md = Md^{-1}J^T K2^{-1} J)
// Iterate 10x: y=Px+c; x += clamp(2y-x,l,u)-y; out=y[:64].

__device__ __forceinline__ float dot4f(float4 a, float4 b) {
  return a.x*b.x + a.y*b.y + a.z*b.z + a.w*b.w;
}
__device__ __forceinline__ void ld4(const float* p, float* d) {
  float4 v = *(const float4*)p;
  d[0] = v.x; d[1] = v.y; d[2] = v.z; d[3] = v.w;
}

// ---------------------------------------------------------------- kernel A
__global__ __launch_bounds__(256) void prep_kernel(
    const float* __restrict__ Qg, const float* __restrict__ Ag,
    const float* __restrict__ Gg,
    float* __restrict__ Pg, float* __restrict__ Bg, float* __restrict__ R2g)
{
  __shared__ float sL[64][68];     // I+Q -> chol L in place; later overlaid by KT
  __shared__ float sS[64][64];     // S = (I+Q)^{-1}
  __shared__ float smem2[5424];    // sLT[64*68] -> later sT[64*48] + sK[48*49]
  __shared__ float sKi[48][52];    // K2^{-1}

  float* sLT = smem2;              // [i*68+j]
  float* sT  = smem2;              // [i*48+j]
  float* sK  = smem2 + 3072;       // [i*49+j]
  float* sKT = &sL[0][0];          // [i*49+j], valid after L dead

  const int tid = threadIdx.x;

  // M1 = Q + I
  for (int t = tid; t < 64*64; t += 256) {
    int i = t >> 6, j = t & 63;
    sL[i][j] = Qg[t] + (i == j ? 1.0f : 0.0f);
  }
  __syncthreads();

  // chol64 in place (wave 0 only, lockstep, no block barriers needed)
  if (tid < 64) {
    for (int j = 0; j < 64; ++j) {
      float tmp = 0.0f;
      if (tid >= j) {
        tmp = sL[tid][j];
        int j4 = j & ~3;
        for (int k = 0; k < j4; k += 4) {
          float4 a = *(const float4*)&sL[tid][k];
          float4 b = *(const float4*)&sL[j][k];
          tmp -= dot4f(a, b);
        }
        for (int k = j4; k < j; ++k) tmp -= sL[tid][k] * sL[j][k];
      }
      float d = sqrtf(__shfl(tmp, j, 64));
      if (tid >= j) sL[tid][j] = (tid == j) ? d : tmp / d;
      __builtin_amdgcn_wave_barrier();
    }
  }
  __syncthreads();

  // LT = L^T
  for (int t = tid; t < 64*64; t += 256) {
    int i = t >> 6, j = t & 63;
    sLT[i*68 + j] = sL[j][i];
  }
  __syncthreads();

  // S = M1^{-1}, column per lane, z fully in registers (static unroll)
  if (tid < 64) {
    const int c = tid;
    float z[64];
    #pragma unroll
    for (int i = 0; i < 64; ++i) {
      float acc = (i == c) ? 1.0f : 0.0f;
      #pragma unroll
      for (int j = 0; j < i; ++j) acc -= sL[i][j] * z[j];
      z[i] = acc / sL[i][i];
    }
    #pragma unroll
    for (int i = 63; i >= 0; --i) {
      float acc = z[i];
      #pragma unroll
      for (int j = i + 1; j < 64; ++j) acc -= sLT[i*68 + j] * z[j];
      z[i] = acc / sL[i][i];
    }
    #pragma unroll
    for (int i = 0; i < 64; ++i) sS[i][c] = z[i];
  }
  __syncthreads();

  // T = S Jx^T : T[i][j] = sum_k S[i][k]*Jx[j][k]   (overwrites sLT region)
  for (int t = tid; t < 64*48; t += 256) {
    int i = t / 48, j = t - i*48;
    const float* jx = (j < 16) ? (Ag + (j << 6)) : (Gg + ((j - 16) << 6));
    float acc = 0.0f;
    for (int k = 0; k < 64; k += 4) {
      float4 s4 = *(const float4*)&sS[i][k];
      float4 x4 = *(const float4*)(jx + k);
      acc += dot4f(s4, x4);
    }
    sT[i*48 + j] = acc;
  }
  __syncthreads();

  // K2 = Jx T + diag(0,I32)   tile 3a x 4b on 192 threads
  if (tid < 192) {
    int ag = tid / 12, bg = tid - ag*12;
    int a0 = ag*3, b0 = bg*4;
    float acc[3][4] = {};
    const float* ja[3];
    #pragma unroll
    for (int r = 0; r < 3; ++r) {
      int a = a0 + r;
      ja[r] = (a < 16) ? (Ag + (a << 6)) : (Gg + ((a - 16) << 6));
    }
    for (int k = 0; k < 64; ++k) {
      float4 tb = *(const float4*)&sT[k*48 + b0];
      #pragma unroll
      for (int r = 0; r < 3; ++r) {
        float jv = ja[r][k];
        acc[r][0] += jv*tb.x; acc[r][1] += jv*tb.y;
        acc[r][2] += jv*tb.z; acc[r][3] += jv*tb.w;
      }
    }
    #pragma unroll
    for (int r = 0; r < 3; ++r)
      #pragma unroll
      for (int q = 0; q < 4; ++q) {
        int a = a0 + r, b = b0 + q;
        sK[a*49 + b] = acc[r][q] + ((a == b && a >= 16) ? 1.0f : 0.0f);
      }
  }
  __syncthreads();

  // chol48 in place (lanes 0..47)
  if (tid < 48) {
    for (int j = 0; j < 48; ++j) {
      float tmp = 0.0f;
      if (tid >= j) {
        tmp = sK[tid*49 + j];
        for (int k = 0; k < j; ++k) tmp -= sK[tid*49 + k] * sK[j*49 + k];
      }
      float d = sqrtf(__shfl(tmp, j, 64));
      if (tid >= j) sK[tid*49 + j] = (tid == j) ? d : tmp / d;
      __builtin_amdgcn_wave_barrier();
    }
  }
  __syncthreads();

  // KT = K^T  (overlays sL region; L is dead now)
  for (int t = tid; t < 48*48; t += 256) {
    int i = t / 48, j = t - i*48;
    sKT[i*49 + j] = sK[j*49 + i];
  }
  __syncthreads();

  // Ki = K2^{-1}, column per lane
  if (tid < 48) {
    const int c = tid;
    float z[48];
    #pragma unroll
    for (int i = 0; i < 48; ++i) {
      float acc = (i == c) ? 1.0f : 0.0f;
      #pragma unroll
      for (int j = 0; j < i; ++j) acc -= sK[i*49 + j] * z[j];
      z[i] = acc / sK[i*49 + i];
    }
    #pragma unroll
    for (int i = 47; i >= 0; --i) {
      float acc = z[i];
      #pragma unroll
      for (int j = i + 1; j < 48; ++j) acc -= sKT[i*49 + j] * z[j];
      z[i] = acc / sK[i*49 + i];
    }
    #pragma unroll
    for (int i = 0; i < 48; ++i) sKi[i][c] = z[i];
  }
  __syncthreads();

  // R2 cols<64: R2[k][c] = sum_m Ki[k][m]*T[c][m]  tile 3k x 4c (256 thr)
  {
    int kg = tid >> 4, cg = tid & 15;
    int k0 = kg*3, c0 = cg*4;
    float acc[3][4] = {};
    for (int m = 0; m < 48; m += 4) {
      float kv[3][4], tv[4][4];
      ld4(&sKi[k0+0][m], kv[0]);
      ld4(&sKi[k0+1][m], kv[1]);
      ld4(&sKi[k0+2][m], kv[2]);
      ld4(&sT[(c0+0)*48 + m], tv[0]);
      ld4(&sT[(c0+1)*48 + m], tv[1]);
      ld4(&sT[(c0+2)*48 + m], tv[2]);
      ld4(&sT[(c0+3)*48 + m], tv[3]);
      #pragma unroll
      for (int r = 0; r < 3; ++r)
        #pragma unroll
        for (int q = 0; q < 4; ++q)
          #pragma unroll
          for (int s = 0; s < 4; ++s)
            acc[r][q] += kv[r][s] * tv[q][s];
    }
    #pragma unroll
    for (int r = 0; r < 3; ++r)
      #pragma unroll
      for (int q = 0; q < 4; ++q) {
        int k = k0 + r, c = c0 + q;
        float v = acc[r][q];
        R2g[k*96 + c] = v;
        Bg[c*112 + 64 + k] = v;       // Bmat[:,64:] = R2^T
      }
  }
  // R2 cols>=64 (selection from Ki)
  for (int t = tid; t < 48*32; t += 256) {
    int k = t >> 5, j = t & 31;
    float v = sKi[k][16 + j];
    R2g[k*96 + 64 + j] = v;
    Bg[(64 + j)*112 + 64 + k] = v;
  }
  __syncthreads();

  // P heavy rows (i<64): P = S_diag - T*R2; tasks = 16 igroups x 24 jchunks
  for (int task = tid; task < 384; task += 256) {
    int ig = task / 24, jc = task - ig*24;
    int i0 = ig*4, j0 = jc*4;
    float acc[4][4];
    #pragma unroll
    for (int r = 0; r < 4; ++r)
      #pragma unroll
      for (int q = 0; q < 4; ++q)
        acc[r][q] = (j0 < 64) ? sS[i0+r][j0+q] : 0.0f;
    for (int m = 0; m < 48; m += 4) {
      float tv[4][4], rv[4][4];
      ld4(&sT[(i0+0)*48 + m], tv[0]);
      ld4(&sT[(i0+1)*48 + m], tv[1]);
      ld4(&sT[(i0+2)*48 + m], tv[2]);
      ld4(&sT[(i0+3)*48 + m], tv[3]);
      ld4(&R2g[(m+0)*96 + j0], rv[0]);
      ld4(&R2g[(m+1)*96 + j0], rv[1]);
      ld4(&R2g[(m+2)*96 + j0], rv[2]);
      ld4(&R2g[(m+3)*96 + j0], rv[3]);
      #pragma unroll
      for (int r = 0; r < 4; ++r)
        #pragma unroll
        for (int q = 0; q < 4; ++q)
          #pragma unroll
          for (int s = 0; s < 4; ++s)
            acc[r][q] -= tv[r][s] * rv[s][q];
    }
    #pragma unroll
    for (int r = 0; r < 4; ++r)
      #pragma unroll
      for (int q = 0; q < 4; ++q) {
        int i = i0 + r, j = j0 + q;
        float v = acc[r][q];
        Pg[i*96 + j] = v;
        if (j0 < 64) Bg[i*112 + j] = -v;   // Bmat[:,:64] = -P[:,:64]
      }
  }
  // P rows >= 64: P[64+a][j] = (64+a==j) - R2[16+a][j]
  for (int t = tid; t < 32*96; t += 256) {
    int a = t / 96, j = t - a*96;
    float v = ((64 + a) == j ? 1.0f : 0.0f) - R2g[(16 + a)*96 + j];
    Pg[(64 + a)*96 + j] = v;
    if (j < 64) Bg[(64 + a)*112 + j] = -v;
  }
}

// ---------------------------------------------------------------- kernel B
#define EB 16   // elements per block

__global__ __launch_bounds__(256) void iter_kernel(
    const float* __restrict__ xg, const float* __restrict__ pg,
    const float* __restrict__ Pg, const float* __restrict__ Bg,
    float* __restrict__ outg)
{
  __shared__ float sP[96][100];
  __shared__ float sX[EB][100];
  __shared__ float sC[EB][96];
  __shared__ float sPar[EB][112];

  const int tid = threadIdx.x;
  const int gbase = blockIdx.x * EB;

  // stage P, x, parms
  const float4* P4 = (const float4*)Pg;
  for (int t = tid; t < 96*24; t += 256) {
    int r = t / 24, kc = t - r*24;
    *(float4*)&sP[r][kc*4] = P4[t];
  }
  const float4* X4 = (const float4*)xg;
  for (int t = tid; t < EB*24; t += 256) {
    int e = t / 24, kc = t - e*24;
    *(float4*)&sX[e][kc*4] = X4[(gbase + e)*24 + kc];
  }
  const float4* Par4 = (const float4*)pg;
  for (int t = tid; t < EB*28; t += 256) {
    int e = t / 28, jc = t - e*28;
    *(float4*)&sPar[e][jc*4] = Par4[(gbase + e)*28 + jc];
  }
  __syncthreads();

  const int tr = tid & 31, te = tid >> 5;
  const int r0 = tr*3, e0 = te*2;

  // c = Bmat @ parms  (each thread: 3 rows x 2 elems)
  {
    const float4* B4 = (const float4*)Bg;
    #pragma unroll
    for (int rr = 0; rr < 3; ++rr) {
      int r = r0 + rr;
      float a0 = 0.0f, a1 = 0.0f;
      for (int jc = 0; jc < 28; ++jc) {
        float4 bm = B4[r*28 + jc];
        float4 p0 = *(const float4*)&sPar[e0][jc*4];
        float4 p1 = *(const float4*)&sPar[e0+1][jc*4];
        a0 += dot4f(bm, p0);
        a1 += dot4f(bm, p1);
      }
      sC[e0][r] = a0;
      sC[e0+1][r] = a1;
    }
  }
  __syncthreads();

  // 10 DR iterations
  for (int it = 0; it < 10; ++it) {
    float acc[3][2];
    #pragma unroll
    for (int rr = 0; rr < 3; ++rr) {
      acc[rr][0] = sC[e0][r0+rr];
      acc[rr][1] = sC[e0+1][r0+rr];
    }
    #pragma unroll
    for (int kc = 0; kc < 24; ++kc) {
      float pv[3][4], xv[2][4];
      ld4(&sP[r0+0][kc*4], pv[0]);
      ld4(&sP[r0+1][kc*4], pv[1]);
      ld4(&sP[r0+2][kc*4], pv[2]);
      ld4(&sX[e0+0][kc*4], xv[0]);
      ld4(&sX[e0+1][kc*4], xv[1]);
      #pragma unroll
      for (int rr = 0; rr < 3; ++rr)
        #pragma unroll
        for (int ee = 0; ee < 2; ++ee)
          #pragma unroll
          for (int s = 0; s < 4; ++s)
            acc[rr][ee] += pv[rr][s] * xv[ee][s];
    }

    if (it < 9) {
      __syncthreads();   // all dot reads of sX done
      #pragma unroll
      for (int rr = 0; rr < 3; ++rr) {
        int r = r0 + rr;
        float lo = (r < 64) ? -1000.0f : 0.0f;
        #pragma unroll
        for (int ee = 0; ee < 2; ++ee) {
          int e = e0 + ee;
          float y  = acc[rr][ee];
          float xo = sX[e][r];
          float v  = 2.0f*y - xo;
          float zc = fminf(fmaxf(v, lo), 1000.0f);
          sX[e][r] = xo + zc - y;
        }
      }
      __syncthreads();   // updates visible for next iteration
    } else {
      #pragma unroll
      for (int rr = 0; rr < 3; ++rr) {
        int r = r0 + rr;
        if (r < 64) {
          outg[(gbase + e0    )*64 + r] = acc[rr][0];
          outg[(gbase + e0 + 1)*64 + r] = acc[rr][1];
        }
      }
    }
  }
}

// ---------------------------------------------------------------- launch
extern "C" void kernel_launch(void* const* d_in, const int* in_sizes, int n_in,
                              void* d_out, int out_size, void* d_ws, size_t ws_size,
                              hipStream_t stream) {
  const float* x     = (const float*)d_in[0];   // (4096, 96)
  const float* parms = (const float*)d_in[1];   // (4096, 112)
  const float* Qg    = (const float*)d_in[2];   // (64, 64)
  const float* Ag    = (const float*)d_in[3];   // (16, 64)
  const float* Gg    = (const float*)d_in[4];   // (32, 64)
  float* out = (float*)d_out;                   // (4096, 64)

  float* ws  = (float*)d_ws;
  float* Pg  = ws;               // 96*96  = 9216
  float* Bg  = ws + 9216;        // 96*112 = 10752
  float* R2g = ws + 9216 + 10752;// 48*96  = 4608

  prep_kernel<<<1, 256, 0, stream>>>(Qg, Ag, Gg, Pg, Bg, R2g);
  iter_kernel<<<4096 / EB, 256, 0, stream>>>(x, parms, Pg, Bg, out);
}